// Round 6
// baseline (574.644 us; speedup 1.0000x reference)
//
#include <hip/hip_runtime.h>
#include <hip/hip_bf16.h>
#include <math.h>

// simple_GAT: 5-layer GAT (heads=1) + BN(eval) + mean-pool + linear.
// R6: k_aggr processes 4 edges/wave-iteration (quarter-wave per edge, ushort8
// gathers) to halve per-edge instruction count; CSR pair array packed into a
// single int (src 17b | dst-local 8b) halving bscatter/bfinal traffic.

#define NN 100000
#define NE 1600000
#define DH 128
#define NL 5
#define NG 64

static constexpr int ET = NE + NN;            // edges + self loops
static constexpr int NBK = (NN + 255) >> 8;   // 391 buckets of 256 dst nodes

typedef __attribute__((ext_vector_type(8))) short bf16x8;
typedef __attribute__((ext_vector_type(4))) float f32x4;

__device__ __forceinline__ float bf2f(unsigned short u) {
    return __uint_as_float(((unsigned int)u) << 16);
}
__device__ __forceinline__ unsigned short f2bf(float v) {
    __hip_bfloat16 h = __float2bfloat16(v);
    return *reinterpret_cast<unsigned short*>(&h);
}

// ---- input prep: x -> bf16, W -> bf16 transposed --------------------------

__global__ __launch_bounds__(256) void k_castx(const float* __restrict__ x,
                                               unsigned short* __restrict__ xb) {
    int i = blockIdx.x * 2048 + threadIdx.x * 8;
    float4 v0 = *(const float4*)(x + i);
    float4 v1 = *(const float4*)(x + i + 4);
    ushort4 a = {f2bf(v0.x), f2bf(v0.y), f2bf(v0.z), f2bf(v0.w)};
    ushort4 b = {f2bf(v1.x), f2bf(v1.y), f2bf(v1.z), f2bf(v1.w)};
    *(ushort4*)(xb + i) = a;
    *(ushort4*)(xb + i + 4) = b;
}

__global__ __launch_bounds__(256) void k_wprep(const float* __restrict__ W,
                                               unsigned short* __restrict__ wtg) {
    int i = blockIdx.x * 256 + threadIdx.x;      // over NL*128*128
    if (i >= NL * DH * DH) return;
    int l = i >> 14, rem = i & 16383;
    int k = rem >> 7, c = rem & 127;
    wtg[(l << 14) + (c << 7) + k] = f2bf(W[i]);  // wtg[l][c][k] = W[l][k][c]
}

// ---- CSR build (bucketed) -------------------------------------------------

__global__ __launch_bounds__(256) void k_bcount(const int* __restrict__ dst,
                                                int* __restrict__ bcnt) {
    __shared__ int h[NBK];
    for (int i = threadIdx.x; i < NBK; i += 256) h[i] = 0;
    __syncthreads();
    int base = blockIdx.x * 4096;
#pragma unroll
    for (int k = 0; k < 16; ++k) {
        int i = base + k * 256 + threadIdx.x;
        if (i < ET) {
            int d = (i < NE) ? dst[i] : (i - NE);
            atomicAdd(&h[d >> 8], 1);
        }
    }
    __syncthreads();
    for (int i = threadIdx.x; i < NBK; i += 256)
        if (h[i]) atomicAdd(&bcnt[i], h[i]);
}

__global__ __launch_bounds__(512) void k_bscan(const int* __restrict__ bcnt,
                                               int* __restrict__ bbase,
                                               int* __restrict__ bcur,
                                               int* __restrict__ row_ptr) {
    __shared__ int sm[512];
    int t = threadIdx.x;
    int v = (t < NBK) ? bcnt[t] : 0;
    sm[t] = v;
    __syncthreads();
    for (int off = 1; off < 512; off <<= 1) {
        int u = (t >= off) ? sm[t - off] : 0;
        __syncthreads();
        sm[t] += u;
        __syncthreads();
    }
    if (t < NBK) { bbase[t] = sm[t] - v; bcur[t] = sm[t] - v; }
    if (t == 0) { bbase[NBK] = ET; row_ptr[NN] = ET; }
}

__global__ __launch_bounds__(512) void k_bscatter(const int* __restrict__ src,
                                                  const int* __restrict__ dst,
                                                  int* __restrict__ bcur,
                                                  int* __restrict__ pairs) {
    __shared__ int lcnt[NBK];
    __shared__ int lbase[NBK];
    for (int i = threadIdx.x; i < NBK; i += 512) lcnt[i] = 0;
    __syncthreads();
    int base = blockIdx.x * 4096;
    int es[8], ed[8], er[8];
#pragma unroll
    for (int k = 0; k < 8; ++k) {
        int i = base + k * 512 + threadIdx.x;
        if (i < ET) {
            int s, d;
            if (i < NE) { s = src[i]; d = dst[i]; } else { s = d = i - NE; }
            es[k] = s; ed[k] = d;
            er[k] = atomicAdd(&lcnt[d >> 8], 1);
        } else {
            ed[k] = -1;
        }
    }
    __syncthreads();
    for (int i = threadIdx.x; i < NBK; i += 512)
        lbase[i] = lcnt[i] ? atomicAdd(&bcur[i], lcnt[i]) : 0;
    __syncthreads();
#pragma unroll
    for (int k = 0; k < 8; ++k) {
        if (ed[k] >= 0) {
            int bk = ed[k] >> 8;
            // pack: src (17 bits) | dst-local (8 bits) << 17
            pairs[lbase[bk] + er[k]] = es[k] | ((ed[k] & 255) << 17);
        }
    }
}

__global__ __launch_bounds__(256) void k_bfinal(const int* __restrict__ pairs,
                                                const int* __restrict__ bbase,
                                                int* __restrict__ row_ptr,
                                                int* __restrict__ csr_src) {
    __shared__ int ldeg[256];
    __shared__ int lcur[256];
    __shared__ int sm[256];
    int b = blockIdx.x, t = threadIdx.x;
    int n0 = b << 8;
    int e0 = bbase[b], e1 = bbase[b + 1];
    ldeg[t] = 0;
    __syncthreads();
    for (int j = e0 + t; j < e1; j += 256)
        atomicAdd(&ldeg[(pairs[j] >> 17) & 255], 1);
    __syncthreads();
    int v = ldeg[t];
    sm[t] = v;
    __syncthreads();
    for (int off = 1; off < 256; off <<= 1) {
        int u = (t >= off) ? sm[t - off] : 0;
        __syncthreads();
        sm[t] += u;
        __syncthreads();
    }
    int excl = sm[t] - v;
    lcur[t] = excl;
    int n = n0 + t;
    if (n < NN) row_ptr[n] = e0 + excl;
    __syncthreads();
    for (int j = e0 + t; j < e1; j += 256) {
        int p = pairs[j];
        int local = atomicAdd(&lcur[(p >> 17) & 255], 1);
        csr_src[e0 + local] = p & 0x1FFFF;
    }
}

// ---- MFMA GEMM: xp = h @ W (bf16 in, fp32 acc) + fused dots ---------------
// Block: 4 waves x 16 rows = 64 rows, full 128 cols. B staged in LDS with
// XOR swizzle (byte ^= (col&7)<<4) for conflict-free ds_read_b128.

__global__ __launch_bounds__(256) void k_gemm(const unsigned short* __restrict__ A,
                                              const unsigned short* __restrict__ Wt,
                                              const float* __restrict__ a_s,
                                              const float* __restrict__ a_d,
                                              unsigned short* __restrict__ xpb,
                                              float* __restrict__ s_node,
                                              float* __restrict__ d_node) {
    __shared__ __align__(16) char lds[32768];
    int tid = threadIdx.x;
    int w = tid >> 6, l = tid & 63;
    int row0 = blockIdx.x * 64;
    {   // stage Wt[col][k] bf16 with swizzle; coalesced global reads
        int col = tid >> 1, seg = tid & 1;
        const char* srcp = (const char*)Wt + col * 256 + seg * 128;
#pragma unroll
        for (int i = 0; i < 8; ++i) {
            int off = seg * 128 + i * 16;
            *(uint4*)(lds + col * 256 + (off ^ ((col & 7) << 4))) =
                *(const uint4*)(srcp + i * 16);
        }
    }
    // A fragments: row = row0 + w*16 + (l&15), k = ks*32 + (l>>4)*8 + 0..7
    int arow = row0 + w * 16 + (l & 15);
    int arc = min(arow, NN - 1);
    const unsigned short* ap = A + (size_t)arc * DH + ((l >> 4) << 3);
    bf16x8 af[4];
#pragma unroll
    for (int ks = 0; ks < 4; ++ks)
        af[ks] = *(const bf16x8*)(ap + ks * 32);
    __syncthreads();

    f32x4 acc[8];
#pragma unroll
    for (int ct = 0; ct < 8; ++ct) acc[ct] = (f32x4){0.f, 0.f, 0.f, 0.f};
#pragma unroll
    for (int ct = 0; ct < 8; ++ct) {
        int col = ct * 16 + (l & 15);
        int cb = col * 256;
        int sw = (col & 7) << 4;
#pragma unroll
        for (int ks = 0; ks < 4; ++ks) {
            bf16x8 bfr = *(const bf16x8*)(lds + cb + ((ks * 64 + ((l >> 4) << 4)) ^ sw));
            acc[ct] = __builtin_amdgcn_mfma_f32_16x16x32_bf16(af[ks], bfr, acc[ct], 0, 0, 0);
        }
    }

    // fused dots: lane covers cols ct*16 + (l&15) for rows (l>>4)*4 + r
    float asv[8], adv[8];
#pragma unroll
    for (int ct = 0; ct < 8; ++ct) {
        asv[ct] = a_s[ct * 16 + (l & 15)];
        adv[ct] = a_d[ct * 16 + (l & 15)];
    }
    float ps[4] = {0.f, 0.f, 0.f, 0.f}, pd[4] = {0.f, 0.f, 0.f, 0.f};
#pragma unroll
    for (int ct = 0; ct < 8; ++ct)
#pragma unroll
        for (int r = 0; r < 4; ++r) {
            ps[r] = fmaf(acc[ct][r], asv[ct], ps[r]);
            pd[r] = fmaf(acc[ct][r], adv[ct], pd[r]);
        }
#pragma unroll
    for (int off = 8; off >= 1; off >>= 1)
#pragma unroll
        for (int r = 0; r < 4; ++r) {
            ps[r] += __shfl_xor(ps[r], off, 64);
            pd[r] += __shfl_xor(pd[r], off, 64);
        }
    int rbase = row0 + w * 16 + ((l >> 4) << 2);
    if ((l & 15) == 0) {
#pragma unroll
        for (int r = 0; r < 4; ++r) {
            int row = rbase + r;
            if (row < NN) { s_node[row] = ps[r]; d_node[row] = pd[r]; }
        }
    }
    // bf16 xp stores: 16-lane groups write 32B contiguous per (ct,r)
#pragma unroll
    for (int r = 0; r < 4; ++r) {
        int row = rbase + r;
        if (row < NN) {
            unsigned short* op = xpb + (size_t)row * DH + (l & 15);
#pragma unroll
            for (int ct = 0; ct < 8; ++ct)
                op[ct * 16] = f2bf(acc[ct][r]);
        }
    }
}

// ---- aggregation: wave per dst node, 4 edges/iteration --------------------
// Quarter-wave (16 lanes) per edge; each lane covers 8 channels via one
// ushort8 (16B) gather. Cross-quarter shfl_xor combine once per node.

__global__ __launch_bounds__(256) void k_aggr(const unsigned short* __restrict__ xpb,
                                              const float* __restrict__ s_node,
                                              const float* __restrict__ d_node,
                                              const int* __restrict__ row_ptr,
                                              const int* __restrict__ csr_src,
                                              const float* __restrict__ bias,
                                              const float* __restrict__ gamma,
                                              const float* __restrict__ beta,
                                              const float* __restrict__ mean,
                                              const float* __restrict__ var,
                                              unsigned short* __restrict__ hout) {
    __shared__ float2 stash[4][128];
    int wid = threadIdx.x >> 6, lane = threadIdx.x & 63;
    int n = blockIdx.x * 4 + wid;
    if (n >= NN) return;
    int s0 = row_ptr[n], s1 = row_ptr[n + 1];
    int deg = s1 - s0;
    float dn = d_node[n];

    // lane-parallel: up to 128 edges -> registers (deg>128 handled in tail)
    int   sidx[2];
    float ev[2];
#pragma unroll
    for (int k = 0; k < 2; ++k) {
        int j = s0 + k * 64 + lane;
        int s = 0;
        float e = -1e30f;
        if (j < s1) {
            s = csr_src[j];
            float t = s_node[s] + dn;
            e = (t >= 0.f) ? t : 0.2f * t;
        }
        sidx[k] = s;
        ev[k] = e;
    }
    float mx = fmaxf(ev[0], ev[1]);
    for (int j = s0 + 128 + lane; j < s1; j += 64) {   // never in practice
        int s = csr_src[j];
        float t = s_node[s] + dn;
        t = (t >= 0.f) ? t : 0.2f * t;
        mx = fmaxf(mx, t);
    }
#pragma unroll
    for (int off = 32; off >= 1; off >>= 1)
        mx = fmaxf(mx, __shfl_xor(mx, off, 64));

    float w0 = (ev[0] > -1e29f) ? __expf(ev[0] - mx) : 0.f;
    float w1 = (ev[1] > -1e29f) ? __expf(ev[1] - mx) : 0.f;
    float denom = w0 + w1;
#pragma unroll
    for (int off = 32; off >= 1; off >>= 1)
        denom += __shfl_xor(denom, off, 64);

    stash[wid][lane]      = make_float2(w0, __int_as_float(sidx[0]));
    stash[wid][64 + lane] = make_float2(w1, __int_as_float(sidx[1]));

    // gather: quarter-wave per edge, ushort8 (16B) per lane, 4 edges/iter
    int qw = lane >> 4, ql = lane & 15;
    float acc[8];
#pragma unroll
    for (int k = 0; k < 8; ++k) acc[k] = 0.f;
    int cnt = min(deg, 128);
    int cq = (cnt + 3) & ~3;
#pragma unroll 2
    for (int jj = 0; jj < cq; jj += 4) {
        float2 p = stash[wid][jj + qw];      // w=0 for padded slots
        float w = p.x;
        int   s = __float_as_int(p.y);
        uint4 v = ((const uint4*)xpb)[((size_t)s << 4) + ql];
        const unsigned short* pv = (const unsigned short*)&v;
#pragma unroll
        for (int k = 0; k < 8; ++k)
            acc[k] = fmaf(w, bf2f(pv[k]), acc[k]);
    }
    // tail fallback for deg>128 (statistically never; kept for correctness)
    for (int j = s0 + 128; j < s1; ++j) {
        int s = csr_src[j];
        float t = s_node[s] + dn;
        t = (t >= 0.f) ? t : 0.2f * t;
        float w = __expf(t - mx);
        denom += w;
        if (qw == 0) {
            uint4 v = ((const uint4*)xpb)[((size_t)s << 4) + ql];
            const unsigned short* pv = (const unsigned short*)&v;
#pragma unroll
            for (int k = 0; k < 8; ++k)
                acc[k] = fmaf(w, bf2f(pv[k]), acc[k]);
        }
    }
    // combine the four quarter-waves (channels identical across quarters)
#pragma unroll
    for (int k = 0; k < 8; ++k) {
        acc[k] += __shfl_xor(acc[k], 16, 64);
        acc[k] += __shfl_xor(acc[k], 32, 64);
    }

    if (qw == 0) {
        float inv = 1.f / denom;     // denom >= 1 (self-loop term)
        int c = ql << 3;
        float4 bi0 = *(const float4*)(bias + c),  bi1 = *(const float4*)(bias + c + 4);
        float4 ga0 = *(const float4*)(gamma + c), ga1 = *(const float4*)(gamma + c + 4);
        float4 be0 = *(const float4*)(beta + c),  be1 = *(const float4*)(beta + c + 4);
        float4 me0 = *(const float4*)(mean + c),  me1 = *(const float4*)(mean + c + 4);
        float4 va0 = *(const float4*)(var + c),   va1 = *(const float4*)(var + c + 4);
        float bi[8] = {bi0.x, bi0.y, bi0.z, bi0.w, bi1.x, bi1.y, bi1.z, bi1.w};
        float ga[8] = {ga0.x, ga0.y, ga0.z, ga0.w, ga1.x, ga1.y, ga1.z, ga1.w};
        float be[8] = {be0.x, be0.y, be0.z, be0.w, be1.x, be1.y, be1.z, be1.w};
        float me[8] = {me0.x, me0.y, me0.z, me0.w, me1.x, me1.y, me1.z, me1.w};
        float va[8] = {va0.x, va0.y, va0.z, va0.w, va1.x, va1.y, va1.z, va1.w};
        unsigned short ov[8];
#pragma unroll
        for (int k = 0; k < 8; ++k) {
            float o = fmaxf(acc[k] * inv + bi[k], 0.f);
            o = (o - me[k]) * (ga[k] * rsqrtf(va[k] + 1e-5f)) + be[k];
            ov[k] = f2bf(o);
        }
        ((uint4*)hout)[((size_t)n << 4) + ql] = *(const uint4*)ov;
    }
}

// ---- mean pool over sorted batch + final linear ---------------------------

__global__ __launch_bounds__(128) void k_pool1(const unsigned short* __restrict__ h,
                                               const int* __restrict__ batch,
                                               float* __restrict__ sums,
                                               int* __restrict__ cnts) {
    int c = threadIdx.x;
    int n0 = blockIdx.x * 64;
    int n1 = min(NN, n0 + 64);
    if (n0 >= NN) return;
    float acc = 0.f;
    int cur = batch[n0];
    int cnt = 0;
    for (int n = n0; n < n1; ++n) {
        int g = batch[n];
        if (g != cur) {
            atomicAdd(&sums[cur * DH + c], acc);
            if (c == 0) atomicAdd(&cnts[cur], cnt);
            acc = 0.f; cnt = 0; cur = g;
        }
        acc += bf2f(h[(size_t)n * DH + c]);
        ++cnt;
    }
    atomicAdd(&sums[cur * DH + c], acc);
    if (c == 0) atomicAdd(&cnts[cur], cnt);
}

__global__ __launch_bounds__(128) void k_pool2(const float* __restrict__ sums,
                                               const int* __restrict__ cnts,
                                               const float* __restrict__ lin_w,
                                               const float* __restrict__ lin_b,
                                               float* __restrict__ out) {
    __shared__ float sm[128];
    int g = blockIdx.x, c = threadIdx.x;
    float cnt = fmaxf((float)cnts[g], 1.f);
    sm[c] = (sums[g * DH + c] / cnt) * lin_w[c];
    __syncthreads();
    for (int off = 64; off >= 1; off >>= 1) {
        if (c < off) sm[c] += sm[c + off];
        __syncthreads();
    }
    if (c == 0) out[g] = sm[0] + lin_b[0];
}

// ---- launch ---------------------------------------------------------------

extern "C" void kernel_launch(void* const* d_in, const int* in_sizes, int n_in,
                              void* d_out, int out_size, void* d_ws, size_t ws_size,
                              hipStream_t stream) {
    const float* x     = (const float*)d_in[0];
    const int*   ei    = (const int*)d_in[1];
    const int*   batch = (const int*)d_in[2];
    const float* W     = (const float*)d_in[3];
    const float* a_src = (const float*)d_in[4];
    const float* a_dst = (const float*)d_in[5];
    const float* b     = (const float*)d_in[6];
    const float* bn_g  = (const float*)d_in[7];
    const float* bn_b  = (const float*)d_in[8];
    const float* bn_m  = (const float*)d_in[9];
    const float* bn_v  = (const float*)d_in[10];
    const float* lin_w = (const float*)d_in[11];
    const float* lin_b = (const float*)d_in[12];
    float* out = (float*)d_out;

    const int* srcp = ei;
    const int* dstp = ei + NE;

    char* wsp = (char*)d_ws;
    size_t off = 0;
    auto alloc = [&](size_t bytes) -> void* {
        void* p = wsp + off;
        off = (off + bytes + 511) & ~((size_t)511);
        return p;
    };
    unsigned short* xpb = (unsigned short*)alloc((size_t)NN * DH * 2);  // bf16 xp
    unsigned short* xb  = (unsigned short*)alloc((size_t)NN * DH * 2);  // bf16 x
    unsigned short* hb  = (unsigned short*)alloc((size_t)NN * DH * 2);  // bf16 h
    unsigned short* wtg = (unsigned short*)alloc((size_t)NL * DH * DH * 2);
    float* s_node  = (float*)alloc((size_t)NN * 4);
    float* d_node  = (float*)alloc((size_t)NN * 4);
    int*   row_ptr = (int*)alloc((size_t)(NN + 1) * 4);
    int*   csr_src = (int*)alloc((size_t)ET * 4);
    int*   pairs   = (int*)alloc((size_t)ET * 4);
    int*   bcnt    = (int*)alloc((size_t)NBK * 4);
    int*   bbase   = (int*)alloc((size_t)(NBK + 1) * 4);
    int*   bcur    = (int*)alloc((size_t)NBK * 4);
    float* sums    = (float*)alloc((size_t)NG * DH * 4);
    int*   cnts    = (int*)alloc((size_t)NG * 4);

    // prep: bf16 casts
    k_castx<<<(NN * DH) / 2048, 256, 0, stream>>>(x, xb);
    k_wprep<<<(NL * DH * DH + 255) / 256, 256, 0, stream>>>(W, wtg);

    // CSR build (bucketed; reused across the 5 layers)
    hipMemsetAsync(bcnt, 0, (size_t)NBK * 4, stream);
    k_bcount<<<(ET + 4095) / 4096, 256, 0, stream>>>(dstp, bcnt);
    k_bscan<<<1, 512, 0, stream>>>(bcnt, bbase, bcur, row_ptr);
    k_bscatter<<<(ET + 4095) / 4096, 512, 0, stream>>>(srcp, dstp, bcur, pairs);
    k_bfinal<<<NBK, 256, 0, stream>>>(pairs, bbase, row_ptr, csr_src);

    for (int l = 0; l < NL; ++l) {
        const unsigned short* hin = (l == 0) ? xb : hb;
        k_gemm<<<(NN + 63) / 64, 256, 0, stream>>>(hin, wtg + (size_t)l * DH * DH,
                                                   a_src + l * DH, a_dst + l * DH,
                                                   xpb, s_node, d_node);
        k_aggr<<<(NN + 3) / 4, 256, 0, stream>>>(xpb, s_node, d_node, row_ptr, csr_src,
                                                 b + l * DH, bn_g + l * DH, bn_b + l * DH,
                                                 bn_m + l * DH, bn_v + l * DH, hb);
    }

    hipMemsetAsync(sums, 0, (size_t)NG * DH * 4, stream);
    hipMemsetAsync(cnts, 0, (size_t)NG * 4, stream);
    k_pool1<<<(NN + 63) / 64, 128, 0, stream>>>(hb, batch, sums, cnts);
    k_pool2<<<NG, 128, 0, stream>>>(sums, cnts, lin_w, lin_b, out);
}